// Round 10
// baseline (107.308 us; speedup 1.0000x reference)
//
#include <hip/hip_runtime.h>

typedef float f32x4 __attribute__((ext_vector_type(4)));
typedef __bf16 bf16x8 __attribute__((ext_vector_type(8)));
typedef unsigned short u16x4 __attribute__((ext_vector_type(4)));
typedef unsigned int u32x4 __attribute__((ext_vector_type(4)));

constexpr int V  = 4096;
constexpr int KS = 5;               // K-split (slabs 832,832,832,832,768)
constexpr int NSLAB = 3 * KS;       // 15 partial slabs

__device__ __forceinline__ unsigned short f2bf(float f) {
    unsigned int u = __float_as_uint(f);
    u += 0x7FFFu + ((u >> 16) & 1u);           // round-to-nearest-even
    return (unsigned short)(u >> 16);
}
__device__ __forceinline__ float bf2f(unsigned short h) {
    return __uint_as_float(((unsigned int)h) << 16);
}

// ---- kernel 1: z = W @ xv + b  -> bf16 (384 x 4096) --------------------
__global__ __launch_bounds__(256) void k_z(const float* __restrict__ x,
                                           const float* __restrict__ W,
                                           const float* __restrict__ b,
                                           unsigned short* __restrict__ zb) {
    __shared__ float Ws[8 * 128];
    __shared__ float bs[8];
    const int rg = blockIdx.x;
    const int vb = blockIdx.y;
    const int t  = threadIdx.x;
    reinterpret_cast<f32x4*>(Ws)[t] = reinterpret_cast<const f32x4*>(W + rg * 1024)[t];
    if (t < 8) bs[t] = b[rg * 8 + t];
    __syncthreads();
    const int v = vb * 1024 + t * 4;
    f32x4 acc[8] = {};
    #pragma unroll 8
    for (int j = 0; j < 128; ++j) {
        f32x4 xv = *reinterpret_cast<const f32x4*>(x + (size_t)j * V + v);
        #pragma unroll
        for (int q = 0; q < 8; ++q) acc[q] += Ws[q * 128 + j] * xv;
    }
    #pragma unroll
    for (int q = 0; q < 8; ++q) {
        u16x4 u;
        #pragma unroll
        for (int j = 0; j < 4; ++j) u[j] = f2bf(acc[q][j] + bs[q]);
        *reinterpret_cast<u16x4*>(zb + (size_t)(rg * 8 + q) * V + v) = u;
    }
}

// ---- kernel 2 (fused): gemm blocks + fifo-streaming blocks share HBM ---
// role A (240): partial[p,kh] = bf16( z[p] @ A[p][k-slab] )  (r7 body verbatim)
// role B (128): fsum = x + sum(fifo[:16] over i,p)           (linear streams)
// bid%3==1 -> B: spreads over all XCDs (gcd(3,8)=1); all 384 blocks
// co-resident (2/CU cap), so B's independent loads fill A's barrier holes.
__global__ __launch_bounds__(256, 2) void k_fused(const unsigned short* __restrict__ zb,
                                                  const float* __restrict__ A,
                                                  const float* __restrict__ x,
                                                  const float* __restrict__ fifo,
                                                  unsigned short* __restrict__ partial,
                                                  float* __restrict__ fsum) {
    __shared__ unsigned int Bt[2][256][20];   // role A only
    const int bid = blockIdx.x;
    const int t   = threadIdx.x;

    if (bid % 3 == 1) {
        // ---------------- role B: x + fifo[:48 slabs] ----------------
        const int rid = bid / 3;                  // 0..127
        const size_t slab = (size_t)128 * V;
        for (int i = 0; i < 4; ++i) {
            const size_t off = ((size_t)(rid + 128 * i) * 256 + t) * 4;
            f32x4 s0 = *reinterpret_cast<const f32x4*>(x + off);
            f32x4 s1 = {}, s2 = {}, s3 = {};
            #pragma unroll
            for (int s = 0; s < 48; ++s) {
                f32x4 fv = *reinterpret_cast<const f32x4*>(fifo + (size_t)s * slab + off);
                switch (s & 3) {
                    case 0: s0 += fv; break;
                    case 1: s1 += fv; break;
                    case 2: s2 += fv; break;
                    default: s3 += fv; break;
                }
            }
            *reinterpret_cast<f32x4*>(fsum + off) = (s0 + s1) + (s2 + s3);
        }
        return;
    }

    // ---------------- role A: r7 gemm body ----------------
    const int aid = bid - (bid + 1) / 3;        // 0..255 over non-B bids
    if (aid >= 240) return;                     // 16 spare blocks idle
    const int nt = aid & 15;
    const int rest = aid >> 4;                  // 0..14
    const int p  = rest % 3;
    const int kh = rest / 3;                    // 0..4
    const int n0    = nt * 256;
    const int kbase = kh * 832;
    const int kend  = (kh == 4) ? 4096 : kbase + 832;

    const int w  = t >> 6;
    const int l  = t & 63;
    const int wm = w >> 1, wn = w & 1;
    const int lrow = l & 15, g = l >> 4;

    const float* Ab = A + (size_t)p * V * V + (size_t)(w * 8) * V + n0 + l * 4;
    const int wswz = (w ^ (l & 3)) << 2;
    const int gp = (g ^ ((lrow >> 2) & 3)) << 2;
    const unsigned short* Zb = zb + ((size_t)p * 128 + wm * 64 + lrow) * V + g * 8;

    f32x4 acc[4][8] = {};
    f32x4 arA[8], arB[8];
    bf16x8 zr[4];

#define LOADA(AR, K) { _Pragma("unroll") for (int j = 0; j < 8; ++j) \
        AR[j] = *reinterpret_cast<const f32x4*>(Ab + (size_t)((K) + j) * V); }

#define LOADZ(K) { _Pragma("unroll") for (int mt = 0; mt < 4; ++mt) \
        zr[mt] = *reinterpret_cast<const bf16x8*>(Zb + (size_t)mt * 16 * V + (K)); }

#define WRITEB(B, AR) { _Pragma("unroll") for (int q = 0; q < 4; ++q) { \
        u32x4 pk; \
        asm("v_cvt_pk_bf16_f32 %0, %1, %2" : "=v"(pk[0]) : "v"(AR[0][q]), "v"(AR[1][q])); \
        asm("v_cvt_pk_bf16_f32 %0, %1, %2" : "=v"(pk[1]) : "v"(AR[2][q]), "v"(AR[3][q])); \
        asm("v_cvt_pk_bf16_f32 %0, %1, %2" : "=v"(pk[2]) : "v"(AR[4][q]), "v"(AR[5][q])); \
        asm("v_cvt_pk_bf16_f32 %0, %1, %2" : "=v"(pk[3]) : "v"(AR[6][q]), "v"(AR[7][q])); \
        *reinterpret_cast<u32x4*>(&Bt[B][l * 4 + q][wswz]) = pk; } }

#define BAR asm volatile("s_waitcnt lgkmcnt(0)\n\ts_barrier" ::: "memory")

#define MFMAP(B) { _Pragma("unroll") for (int nn = 0; nn < 8; ++nn) { \
        bf16x8 bf = *reinterpret_cast<const bf16x8*>(&Bt[B][wn * 128 + nn * 16 + lrow][gp]); \
        _Pragma("unroll") for (int mt = 0; mt < 4; ++mt) \
            acc[mt][nn] = __builtin_amdgcn_mfma_f32_16x16x32_bf16(zr[mt], bf, acc[mt][nn], 0, 0, 0); } }

    LOADA(arA, kbase);
    LOADZ(kbase);

    for (int k0 = kbase; k0 < kend; k0 += 64) {
        const int k1 = k0 + 32;
        const int k2 = (k0 + 64 < kend) ? k0 + 64 : kbase;  // dead-load clamp
        WRITEB(0, arA);              // waits only arA's vmcnt
        LOADA(arB, k1);
        BAR;
        MFMAP(0);
        LOADZ(k1);
        WRITEB(1, arB);
        LOADA(arA, k2);
        BAR;
        MFMAP(1);
        LOADZ(k2);
    }

    // C/D layout: col = lane&15 (n), row = g*4 + reg (m)  [verified r1..r9]
    unsigned short* Pp = partial + (size_t)(p * KS + kh) * 128 * V;
    #pragma unroll
    for (int mt = 0; mt < 4; ++mt)
        #pragma unroll
        for (int nn = 0; nn < 8; ++nn) {
            const size_t base = (size_t)(wm * 64 + mt * 16 + g * 4) * V
                              + n0 + wn * 128 + nn * 16 + lrow;
            #pragma unroll
            for (int r = 0; r < 4; ++r)
                Pp[base + (size_t)r * V] = f2bf(acc[mt][nn][r]);
        }
#undef LOADA
#undef LOADZ
#undef WRITEB
#undef BAR
#undef MFMAP
}

// ---- kernel 3: out = relu(fsum + sum(15 bf16 partials)) ----------------
__global__ __launch_bounds__(256) void k_epi2(const float* __restrict__ fsum,
                                              const unsigned short* __restrict__ partial,
                                              float* __restrict__ out) {
    const size_t off  = ((size_t)blockIdx.x * 256 + threadIdx.x) * 4;
    const size_t slab = (size_t)128 * V;
    f32x4 s0 = *reinterpret_cast<const f32x4*>(fsum + off);
    f32x4 s1 = {};
    #pragma unroll
    for (int q = 0; q < NSLAB; ++q) {
        u16x4 pv = *reinterpret_cast<const u16x4*>(partial + (size_t)q * slab + off);
        f32x4 d;
        #pragma unroll
        for (int j = 0; j < 4; ++j) d[j] = bf2f(pv[j]);
        if (q & 1) s1 += d; else s0 += d;
    }
    f32x4 sum = s0 + s1;
    f32x4 o;
    #pragma unroll
    for (int j = 0; j < 4; ++j) o[j] = fmaxf(sum[j], 0.0f);
    *reinterpret_cast<f32x4*>(out + off) = o;
}

extern "C" void kernel_launch(void* const* d_in, const int* in_sizes, int n_in,
                              void* d_out, int out_size, void* d_ws, size_t ws_size,
                              hipStream_t stream) {
    const float* x    = (const float*)d_in[0];   // (1,128,4096,1)
    const float* A    = (const float*)d_in[1];   // (3,4096,4096)
    const float* fifo = (const float*)d_in[2];   // (17,3,128,4096)
    const float* W    = (const float*)d_in[3];   // (384,128)
    const float* b    = (const float*)d_in[4];   // (384,)
    float* out = (float*)d_out;                  // (1,128,4096) f32

    unsigned short* zb      = (unsigned short*)d_ws;                                     // 3 MB bf16
    unsigned short* partial = (unsigned short*)((char*)d_ws + (size_t)3 * 1024 * 1024);  // 15 MB bf16
    float*          fsum    = (float*)((char*)d_ws + (size_t)18 * 1024 * 1024);          // 2 MB f32

    k_z    <<<dim3(48, 4), 256, 0, stream>>>(x, W, b, zb);
    k_fused<<<dim3(384),   256, 0, stream>>>(zb, A, x, fifo, partial, fsum);
    k_epi2 <<<dim3(512),   256, 0, stream>>>(fsum, partial, out);
}

// Round 11
// 95.509 us; speedup vs baseline: 1.1235x; 1.1235x over previous
//
#include <hip/hip_runtime.h>

typedef float f32x4 __attribute__((ext_vector_type(4)));
typedef __bf16 bf16x8 __attribute__((ext_vector_type(8)));
typedef unsigned short u16x4 __attribute__((ext_vector_type(4)));
typedef unsigned int u32x4 __attribute__((ext_vector_type(4)));

constexpr int V  = 4096;
constexpr int KS = 5;               // K-split (slabs 832,832,832,832,768)
constexpr int NSLAB = 3 * KS;       // 15 partial slabs

__device__ __forceinline__ unsigned short f2bf(float f) {
    unsigned int u = __float_as_uint(f);
    u += 0x7FFFu + ((u >> 16) & 1u);           // round-to-nearest-even
    return (unsigned short)(u >> 16);
}
__device__ __forceinline__ float bf2f(unsigned short h) {
    return __uint_as_float(((unsigned int)h) << 16);
}

// ---- kernel 1: z = W @ xv + b  -> bf16 row-major (384 x 4096) ----------
__global__ __launch_bounds__(256) void k_z(const float* __restrict__ x,
                                           const float* __restrict__ W,
                                           const float* __restrict__ b,
                                           unsigned short* __restrict__ zb) {
    __shared__ float Ws[8 * 128];
    __shared__ float bs[8];
    const int rg = blockIdx.x;
    const int vb = blockIdx.y;
    const int t  = threadIdx.x;
    reinterpret_cast<f32x4*>(Ws)[t] = reinterpret_cast<const f32x4*>(W + rg * 1024)[t];
    if (t < 8) bs[t] = b[rg * 8 + t];
    __syncthreads();
    const int v = vb * 1024 + t * 4;
    f32x4 acc[8] = {};
    #pragma unroll 8
    for (int j = 0; j < 128; ++j) {
        f32x4 xv = *reinterpret_cast<const f32x4*>(x + (size_t)j * V + v);
        #pragma unroll
        for (int q = 0; q < 8; ++q) acc[q] += Ws[q * 128 + j] * xv;
    }
    #pragma unroll
    for (int q = 0; q < 8; ++q) {
        u16x4 u;
        #pragma unroll
        for (int j = 0; j < 4; ++j) u[j] = f2bf(acc[q][j] + bs[q]);
        *reinterpret_cast<u16x4*>(zb + (size_t)(rg * 8 + q) * V + v) = u;
    }
}

// ---- kernel 1b: reformat z into MFMA A-fragment order ------------------
// zf[p][kq(128)][mt(8)][lane(64)][8 bf16]: lane l holds
// z[p*128 + mt*16 + (l&15)][kq*32 + (l>>4)*8 + j]  -> gemm LOADZ becomes
// one dwordx4 per fragment at base + lane*16B (1 KB contiguous).
__global__ __launch_bounds__(256) void k_zf(const unsigned short* __restrict__ zb,
                                            unsigned short* __restrict__ zf) {
    const int p  = blockIdx.x;      // 0..2
    const int kq = blockIdx.y;      // 0..127
    const int t  = threadIdx.x;
    const int sub = t >> 6;         // 0..3
    const int l   = t & 63;
    const int lrow = l & 15, g = l >> 4;
    #pragma unroll
    for (int i = 0; i < 2; ++i) {
        const int mt = sub + i * 4;
        bf16x8 v = *reinterpret_cast<const bf16x8*>(
            zb + (size_t)(p * 128 + mt * 16 + lrow) * V + kq * 32 + g * 8);
        *reinterpret_cast<bf16x8*>(
            zf + ((((size_t)p * 128 + kq) * 8 + mt) * 64 + l) * 8) = v;
    }
}

// ---- kernel 2: partial[p,kh] = bf16( z[p] @ A[p][k-slab] ) -------------
// grid (16 nt, 3 p, 5 kh) = 240 blocks, 256 thr = 4 waves (2M x 2N).
// Tile 128M x 256N, BK=32. r7 body + zfrag loads: EVERY global load in the
// inner loop is now a 1 KB contiguous burst (A: 8/tile, z: 4/phase).
__global__ __launch_bounds__(256, 2) void k_gemm(const unsigned short* __restrict__ zf,
                                                 const float* __restrict__ A,
                                                 unsigned short* __restrict__ partial) {
    // [buf][n(256)][kpair(16) @ pitch 20 u32]  = 40 KB total
    // kp-quad swizzle: stored kp = logical kp XOR (((n>>2)&3)<<2)
    __shared__ unsigned int Bt[2][256][20];

    const int nt = blockIdx.x;     // 0..15
    const int p  = blockIdx.y;     // 0..2
    const int kh = blockIdx.z;     // 0..4
    const int n0    = nt * 256;
    const int kbase = kh * 832;
    const int kend  = (kh == 4) ? 4096 : kbase + 832;

    const int t  = threadIdx.x;
    const int w  = t >> 6;
    const int l  = t & 63;
    const int wm = w >> 1, wn = w & 1;
    const int lrow = l & 15, g = l >> 4;

    // staging read base: rows k + w*8 + j, cols n0 + 4l (1 KB/wave-instr)
    const float* Ab = A + (size_t)p * V * V + (size_t)(w * 8) * V + n0 + l * 4;
    // staging write: n = 4l+q, kp-quad = 4*(w ^ (l&3)); one b128 per q
    const int wswz = (w ^ (l & 3)) << 2;
    // fragment read: n = wn*128 + nn*16 + lrow; swizzled kp-quad:
    const int gp = (g ^ ((lrow >> 2) & 3)) << 2;
    // zfrag base for this wave: fragments (wm*4+mt) at kq = K/32, lane l
    const unsigned short* Zf = zf + ((size_t)p * 128 * 8 + wm * 4) * 512 + l * 8;

    f32x4 acc[4][8] = {};
    f32x4 arA[8], arB[8];
    bf16x8 zr[4];

#define LOADA(AR, K) { _Pragma("unroll") for (int j = 0; j < 8; ++j) \
        AR[j] = *reinterpret_cast<const f32x4*>(Ab + (size_t)((K) + j) * V); }

#define LOADZ(K) { const unsigned short* z_ = Zf + (size_t)((K) >> 5) * 8 * 512; \
        _Pragma("unroll") for (int mt = 0; mt < 4; ++mt) \
        zr[mt] = *reinterpret_cast<const bf16x8*>(z_ + (size_t)mt * 512); }

#define WRITEB(B, AR) { _Pragma("unroll") for (int q = 0; q < 4; ++q) { \
        u32x4 pk; \
        asm("v_cvt_pk_bf16_f32 %0, %1, %2" : "=v"(pk[0]) : "v"(AR[0][q]), "v"(AR[1][q])); \
        asm("v_cvt_pk_bf16_f32 %0, %1, %2" : "=v"(pk[1]) : "v"(AR[2][q]), "v"(AR[3][q])); \
        asm("v_cvt_pk_bf16_f32 %0, %1, %2" : "=v"(pk[2]) : "v"(AR[4][q]), "v"(AR[5][q])); \
        asm("v_cvt_pk_bf16_f32 %0, %1, %2" : "=v"(pk[3]) : "v"(AR[6][q]), "v"(AR[7][q])); \
        *reinterpret_cast<u32x4*>(&Bt[B][l * 4 + q][wswz]) = pk; } }

#define BAR asm volatile("s_waitcnt lgkmcnt(0)\n\ts_barrier" ::: "memory")

#define MFMAP(B) { _Pragma("unroll") for (int nn = 0; nn < 8; ++nn) { \
        bf16x8 bf = *reinterpret_cast<const bf16x8*>(&Bt[B][wn * 128 + nn * 16 + lrow][gp]); \
        _Pragma("unroll") for (int mt = 0; mt < 4; ++mt) \
            acc[mt][nn] = __builtin_amdgcn_mfma_f32_16x16x32_bf16(zr[mt], bf, acc[mt][nn], 0, 0, 0); } }

    // prologue
    LOADA(arA, kbase);
    LOADZ(kbase);

    for (int k0 = kbase; k0 < kend; k0 += 64) {
        const int k1 = k0 + 32;
        const bool pf = (k0 + 64) < kend;
        // phase 0: consume arA,zr(k0); prefetch arB(k1); reload zr(k1) after use
        WRITEB(0, arA);              // waits only arA's vmcnt
        LOADA(arB, k1);
        BAR;
        MFMAP(0);
        LOADZ(k1);
        // phase 1: consume arB,zr(k1); prefetch arA(k0+64); reload zr(k0+64)
        WRITEB(1, arB);
        if (pf) LOADA(arA, k0 + 64);     // no dead tail loads (8 MB HBM saved)
        BAR;
        MFMAP(1);
        if (pf) LOADZ(k0 + 64);
    }

    // C/D layout: col = lane&15 (n), row = g*4 + reg (m)  [verified r1..r10]
    unsigned short* Pp = partial + (size_t)(p * KS + kh) * 128 * V;
    #pragma unroll
    for (int mt = 0; mt < 4; ++mt)
        #pragma unroll
        for (int nn = 0; nn < 8; ++nn) {
            const size_t base = (size_t)(wm * 64 + mt * 16 + g * 4) * V
                              + n0 + wn * 128 + nn * 16 + lrow;
            #pragma unroll
            for (int r = 0; r < 4; ++r)
                Pp[base + (size_t)r * V] = f2bf(acc[mt][nn][r]);
        }
#undef LOADA
#undef LOADZ
#undef WRITEB
#undef BAR
#undef MFMAP
}

// ---- kernel 3: out = relu(x + sum(fifo[:48 slabs]) + sum(15 bf16 partials))
__global__ __launch_bounds__(256) void k_epi(const float* __restrict__ x,
                                             const float* __restrict__ fifo,
                                             const unsigned short* __restrict__ partial,
                                             float* __restrict__ out) {
    const size_t off  = ((size_t)blockIdx.x * 256 + threadIdx.x) * 4;
    const size_t slab = (size_t)128 * V;
    f32x4 s0 = *reinterpret_cast<const f32x4*>(x + off);
    f32x4 s1 = {}, s2 = {}, s3 = {};
    #pragma unroll
    for (int s = 0; s < 48; ++s) {   // fifo[:16] x 3p = first 48 slabs
        f32x4 fv = *reinterpret_cast<const f32x4*>(fifo + (size_t)s * slab + off);
        switch (s & 3) {
            case 0: s0 += fv; break;
            case 1: s1 += fv; break;
            case 2: s2 += fv; break;
            default: s3 += fv; break;
        }
    }
    #pragma unroll
    for (int q = 0; q < NSLAB; ++q) {
        u16x4 pv = *reinterpret_cast<const u16x4*>(partial + (size_t)q * slab + off);
        f32x4 d;
        #pragma unroll
        for (int j = 0; j < 4; ++j) d[j] = bf2f(pv[j]);
        if (q & 1) s1 += d; else s2 += d;
    }
    f32x4 sum = (s0 + s1) + (s2 + s3);
    f32x4 o;
    #pragma unroll
    for (int j = 0; j < 4; ++j) o[j] = fmaxf(sum[j], 0.0f);
    *reinterpret_cast<f32x4*>(out + off) = o;
}

extern "C" void kernel_launch(void* const* d_in, const int* in_sizes, int n_in,
                              void* d_out, int out_size, void* d_ws, size_t ws_size,
                              hipStream_t stream) {
    const float* x    = (const float*)d_in[0];   // (1,128,4096,1)
    const float* A    = (const float*)d_in[1];   // (3,4096,4096)
    const float* fifo = (const float*)d_in[2];   // (17,3,128,4096)
    const float* W    = (const float*)d_in[3];   // (384,128)
    const float* b    = (const float*)d_in[4];   // (384,)
    float* out = (float*)d_out;                  // (1,128,4096) f32

    unsigned short* zb      = (unsigned short*)d_ws;                                     // 3 MB bf16 row-major
    unsigned short* zf      = (unsigned short*)((char*)d_ws + (size_t)3 * 1024 * 1024);  // 3 MB bf16 fragments
    unsigned short* partial = (unsigned short*)((char*)d_ws + (size_t)6 * 1024 * 1024);  // 15 MB bf16

    k_z   <<<dim3(48, 4),     256, 0, stream>>>(x, W, b, zb);
    k_zf  <<<dim3(3, 128),    256, 0, stream>>>(zb, zf);
    k_gemm<<<dim3(16, 3, KS), 256, 0, stream>>>(zf, A, partial);
    k_epi <<<dim3(512),       256, 0, stream>>>(x, fifo, partial, out);
}

// Round 12
// 95.400 us; speedup vs baseline: 1.1248x; 1.0011x over previous
//
#include <hip/hip_runtime.h>

typedef float f32x4 __attribute__((ext_vector_type(4)));
typedef __bf16 bf16x8 __attribute__((ext_vector_type(8)));
typedef unsigned short u16x4 __attribute__((ext_vector_type(4)));
typedef unsigned int u32x4 __attribute__((ext_vector_type(4)));

constexpr int V  = 4096;
constexpr int KS = 5;               // K-split (slabs 832,832,832,832,768)
constexpr int NSLAB = 3 * KS;       // 15 partial slabs
constexpr size_t FSL = (size_t)128 * 4096;   // fifo slab stride (floats)
constexpr int FCOV = 240 * 2048;    // fsum floats covered by gemm blocks

__device__ __forceinline__ unsigned short f2bf(float f) {
    unsigned int u = __float_as_uint(f);
    u += 0x7FFFu + ((u >> 16) & 1u);           // round-to-nearest-even
    return (unsigned short)(u >> 16);
}
__device__ __forceinline__ float bf2f(unsigned short h) {
    return __uint_as_float(((unsigned int)h) << 16);
}

// ---- kernel 1: z = W @ xv + b  -> bf16 row-major (384 x 4096) ----------
__global__ __launch_bounds__(256) void k_z(const float* __restrict__ x,
                                           const float* __restrict__ W,
                                           const float* __restrict__ b,
                                           unsigned short* __restrict__ zb) {
    __shared__ float Ws[8 * 128];
    __shared__ float bs[8];
    const int rg = blockIdx.x;
    const int vb = blockIdx.y;
    const int t  = threadIdx.x;
    reinterpret_cast<f32x4*>(Ws)[t] = reinterpret_cast<const f32x4*>(W + rg * 1024)[t];
    if (t < 8) bs[t] = b[rg * 8 + t];
    __syncthreads();
    const int v = vb * 1024 + t * 4;
    f32x4 acc[8] = {};
    #pragma unroll 8
    for (int j = 0; j < 128; ++j) {
        f32x4 xv = *reinterpret_cast<const f32x4*>(x + (size_t)j * V + v);
        #pragma unroll
        for (int q = 0; q < 8; ++q) acc[q] += Ws[q * 128 + j] * xv;
    }
    #pragma unroll
    for (int q = 0; q < 8; ++q) {
        u16x4 u;
        #pragma unroll
        for (int j = 0; j < 4; ++j) u[j] = f2bf(acc[q][j] + bs[q]);
        *reinterpret_cast<u16x4*>(zb + (size_t)(rg * 8 + q) * V + v) = u;
    }
}

// ---- kernel 2: gemm (r7 body) + in-loop fifo accumulation --------------
// grid (16 nt, 3 p, 5 kh) = 240 blocks, 256 thr = 4 waves (2M x 2N).
// Tile 128M x 256N, BK=32; A loads = 1 KB contiguous bursts (r7).
// Each block also sums its 2048-float slice of (x + fifo[:48 slabs]) via
// 4 linear f32x4 loads/phase, reg-double-buffered (latency hidden 1 phase).
__global__ __launch_bounds__(256, 1) void k_gemm(const unsigned short* __restrict__ zb,
                                                 const float* __restrict__ A,
                                                 const float* __restrict__ x,
                                                 const float* __restrict__ fifo,
                                                 unsigned short* __restrict__ partial,
                                                 float* __restrict__ fsum) {
    // [buf][n(256)][kpair(16) @ pitch 20 u32]; kp-quad XOR swizzle
    __shared__ unsigned int Bt[2][256][20];

    const int nt = blockIdx.x;     // 0..15
    const int p  = blockIdx.y;     // 0..2
    const int kh = blockIdx.z;     // 0..4
    const int n0    = nt * 256;
    const int kbase = kh * 832;
    const int kend  = (kh == 4) ? 4096 : kbase + 832;

    const int t  = threadIdx.x;
    const int w  = t >> 6;
    const int l  = t & 63;
    const int wm = w >> 1, wn = w & 1;
    const int lrow = l & 15, g = l >> 4;

    const float* Ab = A + (size_t)p * V * V + (size_t)(w * 8) * V + n0 + l * 4;
    const int wswz = (w ^ (l & 3)) << 2;
    const int gp = (g ^ ((lrow >> 2) & 3)) << 2;
    const unsigned short* Zb = zb + ((size_t)p * 128 + wm * 64 + lrow) * V + g * 8;

    // fifo slice: block fbid owns floats [fbid*2048, +2048)
    const int fbid = nt + 16 * (p + 3 * kh);            // 0..239
    const size_t fo0 = (size_t)fbid * 2048 + t * 4;
    const size_t fo1 = fo0 + 1024;
    f32x4 facc0 = {}, facc1 = {};
    f32x4 fA0, fA1, fA2, fA3, fB0, fB1, fB2, fB3;
    int fs_issue = 2, fs_done = 0;

    f32x4 acc[4][8] = {};
    f32x4 arA[8], arB[8];
    bf16x8 zr[4];

#define LOADA(AR, K) { _Pragma("unroll") for (int j = 0; j < 8; ++j) \
        AR[j] = *reinterpret_cast<const f32x4*>(Ab + (size_t)((K) + j) * V); }

#define LOADZ(K) { _Pragma("unroll") for (int mt = 0; mt < 4; ++mt) \
        zr[mt] = *reinterpret_cast<const bf16x8*>(Zb + (size_t)mt * 16 * V + (K)); }

#define LOADF(F0, F1, F2, F3) { if (fs_issue < 48) { \
        F0 = *reinterpret_cast<const f32x4*>(fifo + (size_t)fs_issue * FSL + fo0); \
        F1 = *reinterpret_cast<const f32x4*>(fifo + (size_t)fs_issue * FSL + fo1); \
        F2 = *reinterpret_cast<const f32x4*>(fifo + (size_t)(fs_issue + 1) * FSL + fo0); \
        F3 = *reinterpret_cast<const f32x4*>(fifo + (size_t)(fs_issue + 1) * FSL + fo1); \
        fs_issue += 2; } }

#define ACCF(F0, F1, F2, F3) { if (fs_done < 48) { \
        facc0 += F0; facc1 += F1; facc0 += F2; facc1 += F3; fs_done += 2; } }

#define WRITEB(B, AR) { _Pragma("unroll") for (int q = 0; q < 4; ++q) { \
        u32x4 pk; \
        asm("v_cvt_pk_bf16_f32 %0, %1, %2" : "=v"(pk[0]) : "v"(AR[0][q]), "v"(AR[1][q])); \
        asm("v_cvt_pk_bf16_f32 %0, %1, %2" : "=v"(pk[1]) : "v"(AR[2][q]), "v"(AR[3][q])); \
        asm("v_cvt_pk_bf16_f32 %0, %1, %2" : "=v"(pk[2]) : "v"(AR[4][q]), "v"(AR[5][q])); \
        asm("v_cvt_pk_bf16_f32 %0, %1, %2" : "=v"(pk[3]) : "v"(AR[6][q]), "v"(AR[7][q])); \
        *reinterpret_cast<u32x4*>(&Bt[B][l * 4 + q][wswz]) = pk; } }

#define BAR asm volatile("s_waitcnt lgkmcnt(0)\n\ts_barrier" ::: "memory")

#define MFMAP(B) { _Pragma("unroll") for (int nn = 0; nn < 8; ++nn) { \
        bf16x8 bf = *reinterpret_cast<const bf16x8*>(&Bt[B][wn * 128 + nn * 16 + lrow][gp]); \
        _Pragma("unroll") for (int mt = 0; mt < 4; ++mt) \
            acc[mt][nn] = __builtin_amdgcn_mfma_f32_16x16x32_bf16(zr[mt], bf, acc[mt][nn], 0, 0, 0); } }

    // prologue: A(k0), z(k0), fifo slabs (0,1) -> fA
    LOADA(arA, kbase);
    LOADZ(kbase);
    fA0 = *reinterpret_cast<const f32x4*>(fifo + fo0);
    fA1 = *reinterpret_cast<const f32x4*>(fifo + fo1);
    fA2 = *reinterpret_cast<const f32x4*>(fifo + FSL + fo0);
    fA3 = *reinterpret_cast<const f32x4*>(fifo + FSL + fo1);

    for (int k0 = kbase; k0 < kend; k0 += 64) {
        const int k1 = k0 + 32;
        const bool pf = (k0 + 64) < kend;
        // phase even: consume arA,zr(k0); issue arB(k1), fB; accumulate fA
        WRITEB(0, arA);              // waits only arA's vmcnt (fA is younger)
        LOADA(arB, k1);
        LOADF(fB0, fB1, fB2, fB3);
        BAR;
        MFMAP(0);
        ACCF(fA0, fA1, fA2, fA3);    // forced-arrived by zr-wait; issued last phase
        LOADZ(k1);
        // phase odd: consume arB,zr(k1); issue arA(k0+64), fA; accumulate fB
        WRITEB(1, arB);
        if (pf) LOADA(arA, k0 + 64);
        LOADF(fA0, fA1, fA2, fA3);
        BAR;
        MFMAP(1);
        ACCF(fB0, fB1, fB2, fB3);
        if (pf) LOADZ(k0 + 64);
    }

    // C/D layout: col = lane&15 (n), row = g*4 + reg (m)  [verified r1..r11]
    unsigned short* Pp = partial + (size_t)(p * KS + kh) * 128 * V;
    #pragma unroll
    for (int mt = 0; mt < 4; ++mt)
        #pragma unroll
        for (int nn = 0; nn < 8; ++nn) {
            const size_t base = (size_t)(wm * 64 + mt * 16 + g * 4) * V
                              + n0 + wn * 128 + nn * 16 + lrow;
            #pragma unroll
            for (int r = 0; r < 4; ++r)
                Pp[base + (size_t)r * V] = f2bf(acc[mt][nn][r]);
        }

    // fsum slice: x + sum(fifo[:48])
    facc0 += *reinterpret_cast<const f32x4*>(x + fo0);
    facc1 += *reinterpret_cast<const f32x4*>(x + fo1);
    *reinterpret_cast<f32x4*>(fsum + fo0) = facc0;
    *reinterpret_cast<f32x4*>(fsum + fo1) = facc1;
#undef LOADA
#undef LOADZ
#undef LOADF
#undef ACCF
#undef WRITEB
#undef BAR
#undef MFMAP
}

// ---- kernel 3: out = relu(fsum + sum(15 bf16 partials)); tail blocks
// (off >= FCOV) also do the raw fifo sum for the uncovered 32768 floats.
__global__ __launch_bounds__(256) void k_epi2(const float* __restrict__ x,
                                              const float* __restrict__ fifo,
                                              const float* __restrict__ fsum,
                                              const unsigned short* __restrict__ partial,
                                              float* __restrict__ out) {
    const size_t off = ((size_t)blockIdx.x * 256 + threadIdx.x) * 4;
    f32x4 s0, s1 = {};
    if (off < (size_t)FCOV) {
        s0 = *reinterpret_cast<const f32x4*>(fsum + off);
    } else {
        s0 = *reinterpret_cast<const f32x4*>(x + off);
        #pragma unroll
        for (int s = 0; s < 48; ++s) {
            f32x4 fv = *reinterpret_cast<const f32x4*>(fifo + (size_t)s * FSL + off);
            if (s & 1) s1 += fv; else s0 += fv;
        }
    }
    #pragma unroll
    for (int q = 0; q < NSLAB; ++q) {
        u16x4 pv = *reinterpret_cast<const u16x4*>(partial + (size_t)q * FSL + off);
        f32x4 d;
        #pragma unroll
        for (int j = 0; j < 4; ++j) d[j] = bf2f(pv[j]);
        if (q & 1) s1 += d; else s0 += d;
    }
    f32x4 sum = s0 + s1;
    f32x4 o;
    #pragma unroll
    for (int j = 0; j < 4; ++j) o[j] = fmaxf(sum[j], 0.0f);
    *reinterpret_cast<f32x4*>(out + off) = o;
}

extern "C" void kernel_launch(void* const* d_in, const int* in_sizes, int n_in,
                              void* d_out, int out_size, void* d_ws, size_t ws_size,
                              hipStream_t stream) {
    const float* x    = (const float*)d_in[0];   // (1,128,4096,1)
    const float* A    = (const float*)d_in[1];   // (3,4096,4096)
    const float* fifo = (const float*)d_in[2];   // (17,3,128,4096)
    const float* W    = (const float*)d_in[3];   // (384,128)
    const float* b    = (const float*)d_in[4];   // (384,)
    float* out = (float*)d_out;                  // (1,128,4096) f32

    unsigned short* zb      = (unsigned short*)d_ws;                                     // 3 MB bf16
    unsigned short* partial = (unsigned short*)((char*)d_ws + (size_t)3 * 1024 * 1024);  // 15 MB bf16
    float*          fsum    = (float*)((char*)d_ws + (size_t)18 * 1024 * 1024);          // 2 MB f32

    k_z   <<<dim3(48, 4),     256, 0, stream>>>(x, W, b, zb);
    k_gemm<<<dim3(16, 3, KS), 256, 0, stream>>>(zb, A, x, fifo, partial, fsum);
    k_epi2<<<dim3(512),       256, 0, stream>>>(x, fifo, fsum, partial, out);
}